// Round 19
// baseline (339.055 us; speedup 1.0000x reference)
//
#include <hip/hip_runtime.h>
#include <hip/hip_bf16.h>
#include <math.h>

#define B_SZ 16
#define DM 512
#define LSEQ 1024
#define DI 1024
#define DSTATE 16
#define DTR 32
#define MROWS (B_SZ * LSEQ) /* 16384 */
#define NC 16           /* scan chunks */
#define SCH (LSEQ / NC) /* 64 steps per chunk */
#define PF 8            /* scan prefetch depth */

typedef __attribute__((ext_vector_type(8))) short bf16x8;
typedef __attribute__((ext_vector_type(4))) float f32x4;

__device__ inline float bfu2f(unsigned short u) {
  union { unsigned int i; float f; } c; c.i = ((unsigned int)u) << 16; return c.f;
}
__device__ inline unsigned short f2bfu(float f) {
  union { float f; unsigned int i; } c; c.f = f;
  unsigned int r = c.i + 0x7fff + ((c.i >> 16) & 1);
  return (unsigned short)(r >> 16);
}
__device__ inline f32x4 splat4(float x) { return (f32x4){x, x, x, x}; }

// async global->LDS 16B: lds dest is wave-uniform base + lane*16
__device__ inline void gl_lds16(const unsigned short* g, unsigned short* l) {
  __builtin_amdgcn_global_load_lds(
      (const __attribute__((address_space(1))) unsigned int*)g,
      (__attribute__((address_space(3))) unsigned int*)l, 16, 0, 0);
}

// ---------------- transpose x (B,DM,L) -> xtb bf16 (B,L,DM) ----------------
__global__ void transpose_x_k(const float* __restrict__ x, unsigned short* __restrict__ xtb) {
  __shared__ float t[32][33];
  int b = blockIdx.z;
  int l0 = blockIdx.x * 32, dm0 = blockIdx.y * 32;
  int tx = threadIdx.x, ty = threadIdx.y;
  for (int i = ty; i < 32; i += 8)
    t[i][tx] = x[((long)b * DM + dm0 + i) * LSEQ + l0 + tx];
  __syncthreads();
  for (int i = ty; i < 32; i += 8) {
    long o = ((long)b * LSEQ + l0 + i) * DM + dm0 + tx;
    xtb[o] = f2bfu(t[tx][i]);
  }
}

// ---------------- weight transpose: W[K][N] fp32 -> Wt[N][K] bf16 ----------------
__global__ void wtrans_k(const float* __restrict__ W, unsigned short* __restrict__ Wt,
                         int N, int K) {
  __shared__ float t[32][33];
  int n0 = blockIdx.x * 32, k0 = blockIdx.y * 32;
  int tx = threadIdx.x, ty = threadIdx.y;
  for (int i = ty; i < 32; i += 8)
    t[i][tx] = W[(long)(k0 + i) * N + n0 + tx];
  __syncthreads();
  for (int i = ty; i < 32; i += 8)
    Wt[(long)(n0 + i) * K + k0 + tx] = f2bfu(t[tx][i]);
}

// ---------------- bf16 MFMA GEMM, dbuf 2-phase, 4 waves ----------------
// EPI: 0 = fp32 store, 2 = bf16 store of (acc + bf16 residual),
//      3 = bf16 split store (col<DI -> outp, else outp2; uniform per block)
template <int BM, int BN, int WMN, int WNN, int EPI>
__global__ __launch_bounds__(256, 4) void gemm_bt(
    const unsigned short* __restrict__ A, const unsigned short* __restrict__ Bt,
    void* __restrict__ outp, void* __restrict__ outp2,
    const unsigned short* __restrict__ res, int N, int K) {
  constexpr int WM = BM / WMN;
  constexpr int WN = BN / WNN;
  constexpr int MR = WM / 16;
  constexpr int NR = WN / 16;
  __shared__ __align__(16) unsigned short As[2][BM * 32];
  __shared__ __align__(16) unsigned short Bs[2][BN * 32];
  const int tid = threadIdx.x;
  const int lane = tid & 63;
  const int w = tid >> 6;
  const int wm = w / WNN, wn = w % WNN;
  const long rowT = (long)blockIdx.y * BM;
  const long colT = (long)blockIdx.x * BN;

  f32x4 acc[MR][NR];
#pragma unroll
  for (int m = 0; m < MR; ++m)
#pragma unroll
    for (int n = 0; n < NR; ++n)
      acc[m][n] = (f32x4){0.f, 0.f, 0.f, 0.f};

  const int mrow = wm * WM + (lane & 15);
  const int ncol = wn * WN + (lane & 15);
  const int k8 = (lane >> 4) * 8;
  const int srow = (lane >> 2);
  const int scol = (lane & 3) * 8;

  auto STAGE = [&](int buf, int k0) {
#pragma unroll
    for (int i = 0; i < BM / 64; ++i) {
      int r = i * 64 + w * 16;
      gl_lds16(A + (rowT + r + srow) * K + k0 + scol, &As[buf][r * 32]);
    }
#pragma unroll
    for (int i = 0; i < BN / 64; ++i) {
      int r = i * 64 + w * 16;
      gl_lds16(Bt + (colT + r + srow) * K + k0 + scol, &Bs[buf][r * 32]);
    }
  };

  STAGE(0, 0);
  __syncthreads();
  int cur = 0;
  const int NT = K / 32;
  for (int kt = 0; kt < NT; ++kt) {
    if (kt + 1 < NT) STAGE(cur ^ 1, (kt + 1) * 32);  // prefetch next tile (async)
    bf16x8 af[MR], bfr[NR];
#pragma unroll
    for (int m = 0; m < MR; ++m)
      af[m] = *(const bf16x8*)(&As[cur][(mrow + m * 16) * 32 + k8]);
#pragma unroll
    for (int n = 0; n < NR; ++n)
      bfr[n] = *(const bf16x8*)(&Bs[cur][(ncol + n * 16) * 32 + k8]);
#pragma unroll
    for (int m = 0; m < MR; ++m)
#pragma unroll
      for (int n = 0; n < NR; ++n)
        acc[m][n] = __builtin_amdgcn_mfma_f32_16x16x32_bf16(af[m], bfr[n], acc[m][n], 0, 0, 0);
    __syncthreads();  // drains prefetch (vmcnt) + guards LDS reuse
    cur ^= 1;
  }

  if (EPI == 3) {
    unsigned short* obase = (colT < DI) ? (unsigned short*)outp : (unsigned short*)outp2;
    const long csub = (colT < DI) ? 0 : DI;
#pragma unroll
    for (int m = 0; m < MR; ++m)
#pragma unroll
      for (int n = 0; n < NR; ++n)
#pragma unroll
        for (int r = 0; r < 4; ++r) {
          long row = rowT + wm * WM + m * 16 + (lane >> 4) * 4 + r;
          long col = colT + wn * WN + n * 16 + (lane & 15) - csub;
          obase[row * DI + col] = f2bfu(acc[m][n][r]);
        }
  } else {
#pragma unroll
    for (int m = 0; m < MR; ++m)
#pragma unroll
      for (int n = 0; n < NR; ++n)
#pragma unroll
        for (int r = 0; r < 4; ++r) {
          long row = rowT + wm * WM + m * 16 + (lane >> 4) * 4 + r;
          long col = colT + wn * WN + n * 16 + (lane & 15);
          float v = acc[m][n][r];
          if (EPI == 0)
            ((float*)outp)[row * N + col] = v;
          else  // EPI == 2: bf16 store of acc + residual (preLN)
            ((unsigned short*)outp)[row * N + col] =
                f2bfu(v + bfu2f(res[row * N + col]));
        }
  }
}

// ------------- bf16 MFMA GEMM, 8 waves (512 thr), BM=256 x BN=128 tile ----------
template <int BM, int BN, int WMN, int WNN, int EPI>
__global__ __launch_bounds__(512, 4) void gemm_bt8(
    const unsigned short* __restrict__ A, const unsigned short* __restrict__ Bt,
    void* __restrict__ outp, void* __restrict__ outp2,
    const unsigned short* __restrict__ res, int N, int K) {
  constexpr int WM = BM / WMN;   // 64
  constexpr int WN = BN / WNN;   // 64
  constexpr int MR = WM / 16;    // 4
  constexpr int NR = WN / 16;    // 4
  __shared__ __align__(16) unsigned short As[2][BM * 32];
  __shared__ __align__(16) unsigned short Bs[2][BN * 32];
  const int tid = threadIdx.x;
  const int lane = tid & 63;
  const int w = tid >> 6;        // 0..7
  const int wm = w / WNN, wn = w % WNN;
  const long rowT = (long)blockIdx.y * BM;
  const long colT = (long)blockIdx.x * BN;

  f32x4 acc[MR][NR];
#pragma unroll
  for (int m = 0; m < MR; ++m)
#pragma unroll
    for (int n = 0; n < NR; ++n)
      acc[m][n] = (f32x4){0.f, 0.f, 0.f, 0.f};

  const int mrow = wm * WM + (lane & 15);
  const int ncol = wn * WN + (lane & 15);
  const int k8 = (lane >> 4) * 8;
  const int srow = (lane >> 2);
  const int scol = (lane & 3) * 8;

  auto STAGE = [&](int buf, int k0) {
#pragma unroll
    for (int i = 0; i < BM / 128; ++i) {
      int r = i * 128 + w * 16;
      gl_lds16(A + (rowT + r + srow) * K + k0 + scol, &As[buf][r * 32]);
    }
#pragma unroll
    for (int i = 0; i < BN / 128; ++i) {
      int r = i * 128 + w * 16;
      gl_lds16(Bt + (colT + r + srow) * K + k0 + scol, &Bs[buf][r * 32]);
    }
  };

  STAGE(0, 0);
  __syncthreads();
  int cur = 0;
  const int NT = K / 32;
  for (int kt = 0; kt < NT; ++kt) {
    if (kt + 1 < NT) STAGE(cur ^ 1, (kt + 1) * 32);
    bf16x8 af[MR], bfr[NR];
#pragma unroll
    for (int m = 0; m < MR; ++m)
      af[m] = *(const bf16x8*)(&As[cur][(mrow + m * 16) * 32 + k8]);
#pragma unroll
    for (int n = 0; n < NR; ++n)
      bfr[n] = *(const bf16x8*)(&Bs[cur][(ncol + n * 16) * 32 + k8]);
#pragma unroll
    for (int m = 0; m < MR; ++m)
#pragma unroll
      for (int n = 0; n < NR; ++n)
        acc[m][n] = __builtin_amdgcn_mfma_f32_16x16x32_bf16(af[m], bfr[n], acc[m][n], 0, 0, 0);
    __syncthreads();
    cur ^= 1;
  }

  if (EPI == 3) {
    unsigned short* obase = (colT < DI) ? (unsigned short*)outp : (unsigned short*)outp2;
    const long csub = (colT < DI) ? 0 : DI;
#pragma unroll
    for (int m = 0; m < MR; ++m)
#pragma unroll
      for (int n = 0; n < NR; ++n)
#pragma unroll
        for (int r = 0; r < 4; ++r) {
          long row = rowT + wm * WM + m * 16 + (lane >> 4) * 4 + r;
          long col = colT + wn * WN + n * 16 + (lane & 15) - csub;
          obase[row * DI + col] = f2bfu(acc[m][n][r]);
        }
  } else {
#pragma unroll
    for (int m = 0; m < MR; ++m)
#pragma unroll
      for (int n = 0; n < NR; ++n)
#pragma unroll
        for (int r = 0; r < 4; ++r) {
          long row = rowT + wm * WM + m * 16 + (lane >> 4) * 4 + r;
          long col = colT + wn * WN + n * 16 + (lane & 15);
          float v = acc[m][n][r];
          if (EPI == 0)
            ((float*)outp)[row * N + col] = v;
          else
            ((unsigned short*)outp)[row * N + col] =
                f2bfu(v + bfu2f(res[row * N + col]));
        }
  }
}

// ---------------- causal depthwise conv (D_CONV=4) + SiLU ----------------
__global__ __launch_bounds__(256) void conv_silu_k(
    const unsigned short* __restrict__ xi, const float* __restrict__ conv_w,
    const float* __restrict__ conv_b, unsigned short* __restrict__ xcb) {
  int idx = blockIdx.x * 256 + threadIdx.x;
  int d8 = idx & 127;
  long row = idx >> 7;
  int l = (int)(row & (LSEQ - 1));
  int d0 = d8 * 8;
  float acc[8];
  f32x4 w0[8];
#pragma unroll
  for (int j = 0; j < 8; ++j) {
    acc[j] = conv_b[d0 + j];
    w0[j] = *(const f32x4*)(conv_w + (long)(d0 + j) * 4);
  }
#pragma unroll
  for (int k = 0; k < 4; ++k) {
    int ls = l - 3 + k;
    if (ls < 0) continue;
    uint4 raw = *(const uint4*)(xi + (row - 3 + k) * DI + d0);
    const unsigned short* pv = (const unsigned short*)&raw;
#pragma unroll
    for (int j = 0; j < 8; ++j)
      acc[j] = fmaf(bfu2f(pv[j]), w0[j][k], acc[j]);
  }
  unsigned short o[8];
#pragma unroll
  for (int j = 0; j < 8; ++j) {
    float v = acc[j];
    o[j] = f2bfu(v / (1.f + __expf(-v)));
  }
  *(uint4*)(xcb + row * DI + d0) = *(uint4*)o;
}

// ---------------- delta = softplus(dt_in @ W_dt + dt_bias), bf16 out ----------------
__global__ __launch_bounds__(256) void delta_k(
    const float* __restrict__ proj, const float* __restrict__ W_dt,
    const float* __restrict__ dt_bias, unsigned short* __restrict__ delta) {
  __shared__ float wlds[DTR][256];
  const int tid = threadIdx.x;
  const int d0 = blockIdx.x * 256;
  const int d = d0 + tid;
#pragma unroll
  for (int k = 0; k < DTR; ++k)
    wlds[k][tid] = W_dt[(long)k * DI + d0 + tid];
  __syncthreads();
  const float bias = dt_bias[d];
  const long r0 = (long)blockIdx.y * 16;
  const float* pp = proj + r0 * 64;
  float acc[16];
#pragma unroll
  for (int r = 0; r < 16; ++r) acc[r] = bias;
#pragma unroll
  for (int k = 0; k < DTR; ++k) {
    float w = wlds[k][tid];
#pragma unroll
    for (int r = 0; r < 16; ++r)
      acc[r] = fmaf(pp[r * 64 + k], w, acc[r]);
  }
#pragma unroll
  for (int r = 0; r < 16; ++r) {
    float a = acc[r];
    float sp = a > 20.f ? a : __logf(1.f + __expf(a));
    delta[(r0 + r) * DI + d] = f2bfu(sp);
  }
}

// ================= chunked selective scan: 1 thread = 1 d, all 16 states ==========
// LDS-staged B/C (R18's scalar-load variant regressed: per-wave L2 re-fetch +
// lgkmcnt serialization). PF=8 pipeline: grid-limited occupancy (4 waves/SIMD)
// means ILP depth is the only latency-hiding axis left.
__global__ __launch_bounds__(256) void scan_p1(
    const unsigned short* __restrict__ delta, const unsigned short* __restrict__ xcb,
    const float* __restrict__ proj, const float* __restrict__ A_log,
    float* __restrict__ Hbuf, float* __restrict__ sdbuf) {
  __shared__ __align__(16) f32x4 bs[SCH][4]; // B row: 16 floats
  const int tid = threadIdx.x;
  const int b = blockIdx.z;
  const int c = blockIdx.y;
  const int d = blockIdx.x * 256 + tid;
  const long rowbase = (long)b * LSEQ + (long)c * SCH;

  {
    int r = tid >> 2, q = tid & 3;
    bs[r][q] = *(const f32x4*)(proj + (rowbase + r) * 64 + 32 + q * 4);
  }
  __syncthreads();

  const float* Ap = A_log + (long)d * DSTATE;
  bool fast = true;
#pragma unroll
  for (int j = 0; j < DSTATE; ++j)
    fast = fast && (fabsf(__expf(Ap[j]) - (float)(j + 1)) < 1e-3f);

  f32x4 h[4];
#pragma unroll
  for (int j = 0; j < 4; ++j) h[j] = (f32x4){0.f, 0.f, 0.f, 0.f};
  float sumdv = 0.f;
  const unsigned short* dp = delta + rowbase * DI + d;
  const unsigned short* up = xcb + rowbase * DI + d;

  if (fast) {
    float dvb[PF], ub[PF];
#pragma unroll
    for (int j = 0; j < PF; ++j) {
      dvb[j] = bfu2f(dp[j * DI]);
      ub[j] = bfu2f(up[j * DI]);
    }
    for (int g = 0; g < SCH; g += PF) {
      // NOTE: prefetch reads up to PF rows past the chunk (inside d_ws; unused)
      float dvn[PF], un[PF];
#pragma unroll
      for (int j = 0; j < PF; ++j) {
        dvn[j] = bfu2f(dp[(g + PF + j) * DI]);
        un[j] = bfu2f(up[(g + PF + j) * DI]);
      }
#pragma unroll
      for (int j = 0; j < PF; ++j) {
        float dv = dvb[j], u = ub[j];
        sumdv += dv;
        float du = dv * u;
        float q = __expf(-dv);
        float q2 = q * q, q3 = q2 * q, q4 = q2 * q2;
        float q8 = q4 * q4, q12 = q8 * q4;
        f32x4 qv = (f32x4){q, q2, q3, q4};
        f32x4 du4 = splat4(du);
        h[0] = qv * h[0] + du4 * bs[g + j][0];
        h[1] = splat4(q4) * qv * h[1] + du4 * bs[g + j][1];
        h[2] = splat4(q8) * qv * h[2] + du4 * bs[g + j][2];
        h[3] = splat4(q12) * qv * h[3] + du4 * bs[g + j][3];
      }
#pragma unroll
      for (int j = 0; j < PF; ++j) { dvb[j] = dvn[j]; ub[j] = un[j]; }
    }
  } else {
    float A[16];
#pragma unroll
    for (int j = 0; j < DSTATE; ++j) A[j] = -__expf(Ap[j]);
    for (int li = 0; li < SCH; ++li) {
      float dv = bfu2f(dp[li * DI]);
      float u = bfu2f(up[li * DI]);
      sumdv += dv;
      float du = dv * u;
#pragma unroll
      for (int j = 0; j < 4; ++j) {
        f32x4 bv = bs[li][j];
        f32x4 pv = (f32x4){__expf(dv * A[4 * j]), __expf(dv * A[4 * j + 1]),
                           __expf(dv * A[4 * j + 2]), __expf(dv * A[4 * j + 3])};
        h[j] = pv * h[j] + splat4(du) * bv;
      }
    }
  }
  long hoff = (((long)b * NC + c) * DI + d) * DSTATE;
#pragma unroll
  for (int j = 0; j < 4; ++j) *(f32x4*)(Hbuf + hoff + 4 * j) = h[j];
  sdbuf[((long)b * NC + c) * DI + d] = sumdv;
}

// Phase 2: sequential combine over NC chunk summaries per (b,d,s).
__global__ __launch_bounds__(256) void scan_p2(
    const float* __restrict__ A_log, const float* __restrict__ sdbuf,
    float* __restrict__ Hbuf) {
  const int tid = threadIdx.x;
  const int s = tid & 15;
  const int d = blockIdx.x * 16 + (tid >> 4);
  const int b = blockIdx.y;
  const float A = -__expf(A_log[(long)d * DSTATE + s]);
  float hrun = 0.f;
#pragma unroll
  for (int c = 0; c < NC; ++c) {
    long off = (((long)b * NC + c) * DI + d) * DSTATE + s;
    float Hloc = Hbuf[off];
    float sd = sdbuf[((long)b * NC + c) * DI + d];
    Hbuf[off] = hrun;
    hrun = __expf(A * sd) * hrun + Hloc;
  }
}

// Phase 3: re-run chunk with incoming state; emit gated y (bf16).
__global__ __launch_bounds__(256) void scan_p3(
    const unsigned short* __restrict__ delta, const unsigned short* __restrict__ xcb,
    const unsigned short* __restrict__ zb, const float* __restrict__ proj,
    const float* __restrict__ A_log, const float* __restrict__ D_skip,
    const float* __restrict__ Hbuf, unsigned short* __restrict__ yb) {
  __shared__ __align__(16) f32x4 bs[SCH][8]; // B: [0..3], C: [4..7]
  const int tid = threadIdx.x;
  const int b = blockIdx.z;
  const int c = blockIdx.y;
  const int d = blockIdx.x * 256 + tid;
  const long rowbase = (long)b * LSEQ + (long)c * SCH;

#pragma unroll
  for (int k = 0; k < 2; ++k) {
    int i = tid + k * 256;
    int r = i >> 3, q = i & 7;
    bs[r][q] = *(const f32x4*)(proj + (rowbase + r) * 64 + 32 + q * 4);
  }
  __syncthreads();

  const float* Ap = A_log + (long)d * DSTATE;
  bool fast = true;
#pragma unroll
  for (int j = 0; j < DSTATE; ++j)
    fast = fast && (fabsf(__expf(Ap[j]) - (float)(j + 1)) < 1e-3f);

  long hoff = (((long)b * NC + c) * DI + d) * DSTATE;
  f32x4 h[4];
#pragma unroll
  for (int j = 0; j < 4; ++j) h[j] = *(const f32x4*)(Hbuf + hoff + 4 * j);
  const float Dsk = D_skip[d];

  const unsigned short* dp = delta + rowbase * DI + d;
  const unsigned short* up = xcb + rowbase * DI + d;
  const unsigned short* zp = zb + rowbase * DI + d;
  unsigned short* yp = yb + rowbase * DI + d;

  if (fast) {
    float dvb[PF], ub[PF], zvb[PF];
#pragma unroll
    for (int j = 0; j < PF; ++j) {
      dvb[j] = bfu2f(dp[j * DI]);
      ub[j] = bfu2f(up[j * DI]);
      zvb[j] = bfu2f(zp[j * DI]);
    }
    for (int g = 0; g < SCH; g += PF) {
      // NOTE: prefetch reads up to PF rows past the chunk (inside d_ws; unused)
      float dvn[PF], un[PF], zvn[PF];
#pragma unroll
      for (int j = 0; j < PF; ++j) {
        dvn[j] = bfu2f(dp[(g + PF + j) * DI]);
        un[j] = bfu2f(up[(g + PF + j) * DI]);
        zvn[j] = bfu2f(zp[(g + PF + j) * DI]);
      }
#pragma unroll
      for (int j = 0; j < PF; ++j) {
        float dv = dvb[j], u = ub[j], zv = zvb[j];
        float du = dv * u;
        float q = __expf(-dv);
        float q2 = q * q, q3 = q2 * q, q4 = q2 * q2;
        float q8 = q4 * q4, q12 = q8 * q4;
        f32x4 qv = (f32x4){q, q2, q3, q4};
        f32x4 du4 = splat4(du);
        h[0] = qv * h[0] + du4 * bs[g + j][0];
        h[1] = splat4(q4) * qv * h[1] + du4 * bs[g + j][1];
        h[2] = splat4(q8) * qv * h[2] + du4 * bs[g + j][2];
        h[3] = splat4(q12) * qv * h[3] + du4 * bs[g + j][3];
        f32x4 yv = h[0] * bs[g + j][4] + h[1] * bs[g + j][5];
        yv = yv + h[2] * bs[g + j][6] + h[3] * bs[g + j][7];
        float y = (yv[0] + yv[1]) + (yv[2] + yv[3]);
        float yg = (y + u * Dsk) * (zv / (1.f + __expf(-zv)));
        yp[(g + j) * DI] = f2bfu(yg);
      }
#pragma unroll
      for (int j = 0; j < PF; ++j) { dvb[j] = dvn[j]; ub[j] = un[j]; zvb[j] = zvn[j]; }
    }
  } else {
    float A[16];
#pragma unroll
    for (int j = 0; j < DSTATE; ++j) A[j] = -__expf(Ap[j]);
    for (int li = 0; li < SCH; ++li) {
      float dv = bfu2f(dp[li * DI]);
      float u = bfu2f(up[li * DI]);
      float zv = bfu2f(zp[li * DI]);
      float du = dv * u;
      f32x4 yv = (f32x4){0.f, 0.f, 0.f, 0.f};
#pragma unroll
      for (int j = 0; j < 4; ++j) {
        f32x4 pv = (f32x4){__expf(dv * A[4 * j]), __expf(dv * A[4 * j + 1]),
                           __expf(dv * A[4 * j + 2]), __expf(dv * A[4 * j + 3])};
        h[j] = pv * h[j] + splat4(du) * bs[li][j];
        yv = yv + h[j] * bs[li][4 + j];
      }
      float y = (yv[0] + yv[1]) + (yv[2] + yv[3]);
      float yg = (y + u * Dsk) * (zv / (1.f + __expf(-zv)));
      yp[li * DI] = f2bfu(yg);
    }
  }
}

// -------- fused LayerNorm (stats + apply + transpose), bf16 preLN input --------
__global__ __launch_bounds__(256) void ln_fused_k(
    const unsigned short* __restrict__ pre, const float* __restrict__ gamma,
    const float* __restrict__ beta, float* __restrict__ out) {
  __shared__ float t[32][257];  // 32.9 KB, conflict-free transposed read
  const int tid = threadIdx.x;
  const int b = blockIdx.y;
  const int l0 = blockIdx.x * 32;
  const int r = tid >> 3;        // row in tile
  const int c0 = (tid & 7) * 64; // col base
  const long row = (long)b * LSEQ + l0 + r;

  unsigned short vals[64];
#pragma unroll
  for (int k = 0; k < 8; ++k)
    *(uint4*)(vals + k * 8) = *(const uint4*)(pre + row * DM + c0 + k * 8);

  float f[64];
  float s = 0.f, ss = 0.f;
#pragma unroll
  for (int i = 0; i < 64; ++i) {
    float v = bfu2f(vals[i]);
    f[i] = v;
    s += v;
    ss += v * v;
  }
#pragma unroll
  for (int off = 1; off < 8; off <<= 1) {
    s += __shfl_xor(s, off);
    ss += __shfl_xor(ss, off);
  }
  const float m = s * (1.f / DM);
  const float rstd = rsqrtf(ss * (1.f / DM) - m * m + 1e-5f);

#pragma unroll
  for (int i = 0; i < 64; ++i)
    f[i] = (f[i] - m) * rstd * gamma[c0 + i] + beta[c0 + i];

#pragma unroll
  for (int half = 0; half < 2; ++half) {
    __syncthreads();
    if ((c0 >> 8) == half) {
      int cb = c0 - half * 256;
#pragma unroll
      for (int i = 0; i < 64; ++i) t[r][cb + i] = f[i];
    }
    __syncthreads();
    const int tx = tid & 31;       // l index
    for (int i = tid >> 5; i < 256; i += 8) {
      long dm = half * 256 + i;
      out[((long)b * DM + dm) * LSEQ + l0 + tx] = t[tx][i];
    }
  }
}

extern "C" void kernel_launch(void* const* d_in, const int* in_sizes, int n_in,
                              void* d_out, int out_size, void* d_ws, size_t ws_size,
                              hipStream_t stream) {
  const float* x = (const float*)d_in[0];
  const float* W_in = (const float*)d_in[1];
  const float* conv_w = (const float*)d_in[2];
  const float* conv_b = (const float*)d_in[3];
  const float* W_x = (const float*)d_in[4];
  const float* W_dt = (const float*)d_in[5];
  const float* dt_bias = (const float*)d_in[6];
  const float* A_log = (const float*)d_in[7];
  const float* D_skip = (const float*)d_in[8];
  const float* W_out = (const float*)d_in[9];
  const float* gamma = (const float*)d_in[10];
  const float* beta = (const float*)d_in[11];
  float* out = (float*)d_out;

  char* p = (char*)d_ws;
  auto alloc = [&](size_t bytes) {
    char* r = p;
    p += (bytes + 255) & ~(size_t)255;
    return r;
  };
  unsigned short* xtb = (unsigned short*)alloc((size_t)MROWS * DM * 2);      // 16 MB
  unsigned short* xib = (unsigned short*)alloc((size_t)MROWS * DI * 2);      // 32 MB (reused as yb)
  unsigned short* zb  = (unsigned short*)alloc((size_t)MROWS * DI * 2);      // 32 MB
  unsigned short* xcb = (unsigned short*)alloc((size_t)MROWS * DI * 2);      // 32 MB
  float* proj = (float*)alloc((size_t)MROWS * 64 * 4);                       // 4 MB
  unsigned short* dbuf = (unsigned short*)alloc((size_t)MROWS * DI * 2);     // 32 MB (reused as preLN bf16)
  float* sdbuf = (float*)alloc((size_t)B_SZ * NC * DI * 4);                  // 1 MB
  unsigned short* WinT = (unsigned short*)alloc((size_t)2 * DI * DM * 2);    // 2 MB
  unsigned short* WxT = (unsigned short*)alloc((size_t)64 * DI * 2);
  unsigned short* WoutT = (unsigned short*)alloc((size_t)DM * DI * 2);       // 1 MB
  unsigned short* yb = xib;                 // xi dead after conv
  unsigned short* preLNb = dbuf;            // delta dead after scan (bf16 preLN)
  // Hbuf (16.8 MB) lives in d_out: dead scratch until ln_fused fully overwrites it.
  float* Hbuf = out;

  transpose_x_k<<<dim3(LSEQ / 32, DM / 32, B_SZ), dim3(32, 8), 0, stream>>>(x, xtb);
  wtrans_k<<<dim3(2 * DI / 32, DM / 32), dim3(32, 8), 0, stream>>>(W_in, WinT, 2 * DI, DM);
  wtrans_k<<<dim3(64 / 32, DI / 32), dim3(32, 8), 0, stream>>>(W_x, WxT, 64, DI);
  wtrans_k<<<dim3(DM / 32, DI / 32), dim3(32, 8), 0, stream>>>(W_out, WoutT, DM, DI);

  // xz = xt @ W_in  (M=16384, N=2048, K=512) -> split bf16 stores xi / z
  gemm_bt8<256, 128, 4, 2, 3><<<dim3(2 * DI / 128, MROWS / 256), 512, 0, stream>>>(
      xtb, WinT, xib, zb, nullptr, 2 * DI, DM);
  // conv + silu -> xcb
  conv_silu_k<<<(MROWS * 128) / 256, 256, 0, stream>>>(xib, conv_w, conv_b, xcb);
  // proj = xc @ W_x (M=16384, N=64, K=1024), fp32 out
  gemm_bt<64, 64, 4, 1, 0><<<dim3(1, MROWS / 64), 256, 0, stream>>>(
      xcb, WxT, proj, nullptr, nullptr, 64, DI);
  // delta = softplus(dt_in @ W_dt + bias), bf16 (W via LDS, 16-row batch)
  delta_k<<<dim3(DI / 256, MROWS / 16), 256, 0, stream>>>(proj, W_dt, dt_bias, dbuf);
  // chunked selective scan (1 thread per d, 16 states, PF=8 pipeline)
  scan_p1<<<dim3(DI / 256, NC, B_SZ), 256, 0, stream>>>(dbuf, xcb, proj, A_log, Hbuf, sdbuf);
  scan_p2<<<dim3(DI / 16, B_SZ), 256, 0, stream>>>(A_log, sdbuf, Hbuf);
  scan_p3<<<dim3(DI / 256, NC, B_SZ), 256, 0, stream>>>(dbuf, xcb, zb, proj, A_log, D_skip,
                                                        Hbuf, yb);
  // preLN = y @ W_out + xt (bf16 store; M=16384, N=512, K=1024)
  gemm_bt<128, 128, 2, 2, 2><<<dim3(DM / 128, MROWS / 128), 256, 0, stream>>>(
      yb, WoutT, preLNb, nullptr, xtb, DM, DI);
  // fused LayerNorm + final transpose
  ln_fused_k<<<dim3(LSEQ / 32, B_SZ), 256, 0, stream>>>(preLNb, gamma, beta, out);
}

// Round 20
// 300.286 us; speedup vs baseline: 1.1291x; 1.1291x over previous
//
#include <hip/hip_runtime.h>
#include <hip/hip_bf16.h>
#include <math.h>

#define B_SZ 16
#define DM 512
#define LSEQ 1024
#define DI 1024
#define DSTATE 16
#define DTR 32
#define MROWS (B_SZ * LSEQ) /* 16384 */
#define NC 16           /* scan chunks */
#define SCH (LSEQ / NC) /* 64 steps per chunk */
#define PF 4            /* scan prefetch depth */

typedef __attribute__((ext_vector_type(8))) short bf16x8;
typedef __attribute__((ext_vector_type(4))) float f32x4;

__device__ inline float bfu2f(unsigned short u) {
  union { unsigned int i; float f; } c; c.i = ((unsigned int)u) << 16; return c.f;
}
__device__ inline unsigned short f2bfu(float f) {
  union { float f; unsigned int i; } c; c.f = f;
  unsigned int r = c.i + 0x7fff + ((c.i >> 16) & 1);
  return (unsigned short)(r >> 16);
}
__device__ inline f32x4 splat4(float x) { return (f32x4){x, x, x, x}; }

// async global->LDS 16B: lds dest is wave-uniform base + lane*16
__device__ inline void gl_lds16(const unsigned short* g, unsigned short* l) {
  __builtin_amdgcn_global_load_lds(
      (const __attribute__((address_space(1))) unsigned int*)g,
      (__attribute__((address_space(3))) unsigned int*)l, 16, 0, 0);
}

// ---------------- transpose x (B,DM,L) -> xtb bf16 (B,L,DM) ----------------
__global__ void transpose_x_k(const float* __restrict__ x, unsigned short* __restrict__ xtb) {
  __shared__ float t[32][33];
  int b = blockIdx.z;
  int l0 = blockIdx.x * 32, dm0 = blockIdx.y * 32;
  int tx = threadIdx.x, ty = threadIdx.y;
  for (int i = ty; i < 32; i += 8)
    t[i][tx] = x[((long)b * DM + dm0 + i) * LSEQ + l0 + tx];
  __syncthreads();
  for (int i = ty; i < 32; i += 8) {
    long o = ((long)b * LSEQ + l0 + i) * DM + dm0 + tx;
    xtb[o] = f2bfu(t[tx][i]);
  }
}

// ---------------- weight transpose: W[K][N] fp32 -> Wt[N][K] bf16 ----------------
__global__ void wtrans_k(const float* __restrict__ W, unsigned short* __restrict__ Wt,
                         int N, int K) {
  __shared__ float t[32][33];
  int n0 = blockIdx.x * 32, k0 = blockIdx.y * 32;
  int tx = threadIdx.x, ty = threadIdx.y;
  for (int i = ty; i < 32; i += 8)
    t[i][tx] = W[(long)(k0 + i) * N + n0 + tx];
  __syncthreads();
  for (int i = ty; i < 32; i += 8)
    Wt[(long)(n0 + i) * K + k0 + tx] = f2bfu(t[tx][i]);
}

// ---------------- bf16 MFMA GEMM, dbuf 2-phase, 4 waves ----------------
// EPI: 0 = fp32 store, 2 = bf16 store of (acc + bf16 residual),
//      3 = bf16 split store (col<DI -> outp, else outp2; uniform per block)
template <int BM, int BN, int WMN, int WNN, int EPI>
__global__ __launch_bounds__(256, 4) void gemm_bt(
    const unsigned short* __restrict__ A, const unsigned short* __restrict__ Bt,
    void* __restrict__ outp, void* __restrict__ outp2,
    const unsigned short* __restrict__ res, int N, int K) {
  constexpr int WM = BM / WMN;
  constexpr int WN = BN / WNN;
  constexpr int MR = WM / 16;
  constexpr int NR = WN / 16;
  __shared__ __align__(16) unsigned short As[2][BM * 32];
  __shared__ __align__(16) unsigned short Bs[2][BN * 32];
  const int tid = threadIdx.x;
  const int lane = tid & 63;
  const int w = tid >> 6;
  const int wm = w / WNN, wn = w % WNN;
  const long rowT = (long)blockIdx.y * BM;
  const long colT = (long)blockIdx.x * BN;

  f32x4 acc[MR][NR];
#pragma unroll
  for (int m = 0; m < MR; ++m)
#pragma unroll
    for (int n = 0; n < NR; ++n)
      acc[m][n] = (f32x4){0.f, 0.f, 0.f, 0.f};

  const int mrow = wm * WM + (lane & 15);
  const int ncol = wn * WN + (lane & 15);
  const int k8 = (lane >> 4) * 8;
  const int srow = (lane >> 2);
  const int scol = (lane & 3) * 8;

  auto STAGE = [&](int buf, int k0) {
#pragma unroll
    for (int i = 0; i < BM / 64; ++i) {
      int r = i * 64 + w * 16;
      gl_lds16(A + (rowT + r + srow) * K + k0 + scol, &As[buf][r * 32]);
    }
#pragma unroll
    for (int i = 0; i < BN / 64; ++i) {
      int r = i * 64 + w * 16;
      gl_lds16(Bt + (colT + r + srow) * K + k0 + scol, &Bs[buf][r * 32]);
    }
  };

  STAGE(0, 0);
  __syncthreads();
  int cur = 0;
  const int NT = K / 32;
  for (int kt = 0; kt < NT; ++kt) {
    if (kt + 1 < NT) STAGE(cur ^ 1, (kt + 1) * 32);  // prefetch next tile (async)
    bf16x8 af[MR], bfr[NR];
#pragma unroll
    for (int m = 0; m < MR; ++m)
      af[m] = *(const bf16x8*)(&As[cur][(mrow + m * 16) * 32 + k8]);
#pragma unroll
    for (int n = 0; n < NR; ++n)
      bfr[n] = *(const bf16x8*)(&Bs[cur][(ncol + n * 16) * 32 + k8]);
#pragma unroll
    for (int m = 0; m < MR; ++m)
#pragma unroll
      for (int n = 0; n < NR; ++n)
        acc[m][n] = __builtin_amdgcn_mfma_f32_16x16x32_bf16(af[m], bfr[n], acc[m][n], 0, 0, 0);
    __syncthreads();  // drains prefetch (vmcnt) + guards LDS reuse
    cur ^= 1;
  }

  if (EPI == 3) {
    unsigned short* obase = (colT < DI) ? (unsigned short*)outp : (unsigned short*)outp2;
    const long csub = (colT < DI) ? 0 : DI;
#pragma unroll
    for (int m = 0; m < MR; ++m)
#pragma unroll
      for (int n = 0; n < NR; ++n)
#pragma unroll
        for (int r = 0; r < 4; ++r) {
          long row = rowT + wm * WM + m * 16 + (lane >> 4) * 4 + r;
          long col = colT + wn * WN + n * 16 + (lane & 15) - csub;
          obase[row * DI + col] = f2bfu(acc[m][n][r]);
        }
  } else {
#pragma unroll
    for (int m = 0; m < MR; ++m)
#pragma unroll
      for (int n = 0; n < NR; ++n)
#pragma unroll
        for (int r = 0; r < 4; ++r) {
          long row = rowT + wm * WM + m * 16 + (lane >> 4) * 4 + r;
          long col = colT + wn * WN + n * 16 + (lane & 15);
          float v = acc[m][n][r];
          if (EPI == 0)
            ((float*)outp)[row * N + col] = v;
          else  // EPI == 2: bf16 store of acc + residual (preLN)
            ((unsigned short*)outp)[row * N + col] =
                f2bfu(v + bfu2f(res[row * N + col]));
        }
  }
}

// ------------- bf16 MFMA GEMM, 8 waves (512 thr), BM=256 x BN=128 tile ----------
template <int BM, int BN, int WMN, int WNN, int EPI>
__global__ __launch_bounds__(512, 4) void gemm_bt8(
    const unsigned short* __restrict__ A, const unsigned short* __restrict__ Bt,
    void* __restrict__ outp, void* __restrict__ outp2,
    const unsigned short* __restrict__ res, int N, int K) {
  constexpr int WM = BM / WMN;   // 64
  constexpr int WN = BN / WNN;   // 64
  constexpr int MR = WM / 16;    // 4
  constexpr int NR = WN / 16;    // 4
  __shared__ __align__(16) unsigned short As[2][BM * 32];
  __shared__ __align__(16) unsigned short Bs[2][BN * 32];
  const int tid = threadIdx.x;
  const int lane = tid & 63;
  const int w = tid >> 6;        // 0..7
  const int wm = w / WNN, wn = w % WNN;
  const long rowT = (long)blockIdx.y * BM;
  const long colT = (long)blockIdx.x * BN;

  f32x4 acc[MR][NR];
#pragma unroll
  for (int m = 0; m < MR; ++m)
#pragma unroll
    for (int n = 0; n < NR; ++n)
      acc[m][n] = (f32x4){0.f, 0.f, 0.f, 0.f};

  const int mrow = wm * WM + (lane & 15);
  const int ncol = wn * WN + (lane & 15);
  const int k8 = (lane >> 4) * 8;
  const int srow = (lane >> 2);
  const int scol = (lane & 3) * 8;

  auto STAGE = [&](int buf, int k0) {
#pragma unroll
    for (int i = 0; i < BM / 128; ++i) {
      int r = i * 128 + w * 16;
      gl_lds16(A + (rowT + r + srow) * K + k0 + scol, &As[buf][r * 32]);
    }
#pragma unroll
    for (int i = 0; i < BN / 128; ++i) {
      int r = i * 128 + w * 16;
      gl_lds16(Bt + (colT + r + srow) * K + k0 + scol, &Bs[buf][r * 32]);
    }
  };

  STAGE(0, 0);
  __syncthreads();
  int cur = 0;
  const int NT = K / 32;
  for (int kt = 0; kt < NT; ++kt) {
    if (kt + 1 < NT) STAGE(cur ^ 1, (kt + 1) * 32);
    bf16x8 af[MR], bfr[NR];
#pragma unroll
    for (int m = 0; m < MR; ++m)
      af[m] = *(const bf16x8*)(&As[cur][(mrow + m * 16) * 32 + k8]);
#pragma unroll
    for (int n = 0; n < NR; ++n)
      bfr[n] = *(const bf16x8*)(&Bs[cur][(ncol + n * 16) * 32 + k8]);
#pragma unroll
    for (int m = 0; m < MR; ++m)
#pragma unroll
      for (int n = 0; n < NR; ++n)
        acc[m][n] = __builtin_amdgcn_mfma_f32_16x16x32_bf16(af[m], bfr[n], acc[m][n], 0, 0, 0);
    __syncthreads();
    cur ^= 1;
  }

  if (EPI == 3) {
    unsigned short* obase = (colT < DI) ? (unsigned short*)outp : (unsigned short*)outp2;
    const long csub = (colT < DI) ? 0 : DI;
#pragma unroll
    for (int m = 0; m < MR; ++m)
#pragma unroll
      for (int n = 0; n < NR; ++n)
#pragma unroll
        for (int r = 0; r < 4; ++r) {
          long row = rowT + wm * WM + m * 16 + (lane >> 4) * 4 + r;
          long col = colT + wn * WN + n * 16 + (lane & 15) - csub;
          obase[row * DI + col] = f2bfu(acc[m][n][r]);
        }
  } else {
#pragma unroll
    for (int m = 0; m < MR; ++m)
#pragma unroll
      for (int n = 0; n < NR; ++n)
#pragma unroll
        for (int r = 0; r < 4; ++r) {
          long row = rowT + wm * WM + m * 16 + (lane >> 4) * 4 + r;
          long col = colT + wn * WN + n * 16 + (lane & 15);
          float v = acc[m][n][r];
          if (EPI == 0)
            ((float*)outp)[row * N + col] = v;
          else
            ((unsigned short*)outp)[row * N + col] =
                f2bfu(v + bfu2f(res[row * N + col]));
        }
  }
}

// ---------------- causal depthwise conv (D_CONV=4) + SiLU ----------------
__global__ __launch_bounds__(256) void conv_silu_k(
    const unsigned short* __restrict__ xi, const float* __restrict__ conv_w,
    const float* __restrict__ conv_b, unsigned short* __restrict__ xcb) {
  int idx = blockIdx.x * 256 + threadIdx.x;
  int d8 = idx & 127;
  long row = idx >> 7;
  int l = (int)(row & (LSEQ - 1));
  int d0 = d8 * 8;
  float acc[8];
  f32x4 w0[8];
#pragma unroll
  for (int j = 0; j < 8; ++j) {
    acc[j] = conv_b[d0 + j];
    w0[j] = *(const f32x4*)(conv_w + (long)(d0 + j) * 4);
  }
#pragma unroll
  for (int k = 0; k < 4; ++k) {
    int ls = l - 3 + k;
    if (ls < 0) continue;
    uint4 raw = *(const uint4*)(xi + (row - 3 + k) * DI + d0);
    const unsigned short* pv = (const unsigned short*)&raw;
#pragma unroll
    for (int j = 0; j < 8; ++j)
      acc[j] = fmaf(bfu2f(pv[j]), w0[j][k], acc[j]);
  }
  unsigned short o[8];
#pragma unroll
  for (int j = 0; j < 8; ++j) {
    float v = acc[j];
    o[j] = f2bfu(v / (1.f + __expf(-v)));
  }
  *(uint4*)(xcb + row * DI + d0) = *(uint4*)o;
}

// ---------------- delta = softplus(dt_in @ W_dt + dt_bias), bf16 out ----------------
__global__ __launch_bounds__(256) void delta_k(
    const float* __restrict__ proj, const float* __restrict__ W_dt,
    const float* __restrict__ dt_bias, unsigned short* __restrict__ delta) {
  __shared__ float wlds[DTR][256];
  const int tid = threadIdx.x;
  const int d0 = blockIdx.x * 256;
  const int d = d0 + tid;
#pragma unroll
  for (int k = 0; k < DTR; ++k)
    wlds[k][tid] = W_dt[(long)k * DI + d0 + tid];
  __syncthreads();
  const float bias = dt_bias[d];
  const long r0 = (long)blockIdx.y * 16;
  const float* pp = proj + r0 * 64;
  float acc[16];
#pragma unroll
  for (int r = 0; r < 16; ++r) acc[r] = bias;
#pragma unroll
  for (int k = 0; k < DTR; ++k) {
    float w = wlds[k][tid];
#pragma unroll
    for (int r = 0; r < 16; ++r)
      acc[r] = fmaf(pp[r * 64 + k], w, acc[r]);
  }
#pragma unroll
  for (int r = 0; r < 16; ++r) {
    float a = acc[r];
    float sp = a > 20.f ? a : __logf(1.f + __expf(a));
    delta[(r0 + r) * DI + d] = f2bfu(sp);
  }
}

// ================= chunked selective scan: 1 thread = 1 d, all 16 states ==========
// PF=4 pipeline, LDS-staged B/C. (R18 scalar-pipe and R19 PF=8 both regressed;
// this is the measured optimum of the explored scan design space.)
__global__ __launch_bounds__(256) void scan_p1(
    const unsigned short* __restrict__ delta, const unsigned short* __restrict__ xcb,
    const float* __restrict__ proj, const float* __restrict__ A_log,
    float* __restrict__ Hbuf, float* __restrict__ sdbuf) {
  __shared__ __align__(16) f32x4 bs[SCH][4]; // B row: 16 floats
  const int tid = threadIdx.x;
  const int b = blockIdx.z;
  const int c = blockIdx.y;
  const int d = blockIdx.x * 256 + tid;
  const long rowbase = (long)b * LSEQ + (long)c * SCH;

  {
    int r = tid >> 2, q = tid & 3;
    bs[r][q] = *(const f32x4*)(proj + (rowbase + r) * 64 + 32 + q * 4);
  }
  __syncthreads();

  const float* Ap = A_log + (long)d * DSTATE;
  bool fast = true;
#pragma unroll
  for (int j = 0; j < DSTATE; ++j)
    fast = fast && (fabsf(__expf(Ap[j]) - (float)(j + 1)) < 1e-3f);

  f32x4 h[4];
#pragma unroll
  for (int j = 0; j < 4; ++j) h[j] = (f32x4){0.f, 0.f, 0.f, 0.f};
  float sumdv = 0.f;
  const unsigned short* dp = delta + rowbase * DI + d;
  const unsigned short* up = xcb + rowbase * DI + d;

  if (fast) {
    float dvb[PF], ub[PF];
#pragma unroll
    for (int j = 0; j < PF; ++j) {
      dvb[j] = bfu2f(dp[j * DI]);
      ub[j] = bfu2f(up[j * DI]);
    }
    for (int g = 0; g < SCH; g += PF) {
      // NOTE: prefetch reads up to PF rows past the chunk (inside d_ws; unused)
      float dvn[PF], un[PF];
#pragma unroll
      for (int j = 0; j < PF; ++j) {
        dvn[j] = bfu2f(dp[(g + PF + j) * DI]);
        un[j] = bfu2f(up[(g + PF + j) * DI]);
      }
#pragma unroll
      for (int j = 0; j < PF; ++j) {
        float dv = dvb[j], u = ub[j];
        sumdv += dv;
        float du = dv * u;
        float q = __expf(-dv);
        float q2 = q * q, q3 = q2 * q, q4 = q2 * q2;
        float q8 = q4 * q4, q12 = q8 * q4;
        f32x4 qv = (f32x4){q, q2, q3, q4};
        f32x4 du4 = splat4(du);
        h[0] = qv * h[0] + du4 * bs[g + j][0];
        h[1] = splat4(q4) * qv * h[1] + du4 * bs[g + j][1];
        h[2] = splat4(q8) * qv * h[2] + du4 * bs[g + j][2];
        h[3] = splat4(q12) * qv * h[3] + du4 * bs[g + j][3];
      }
#pragma unroll
      for (int j = 0; j < PF; ++j) { dvb[j] = dvn[j]; ub[j] = un[j]; }
    }
  } else {
    float A[16];
#pragma unroll
    for (int j = 0; j < DSTATE; ++j) A[j] = -__expf(Ap[j]);
    for (int li = 0; li < SCH; ++li) {
      float dv = bfu2f(dp[li * DI]);
      float u = bfu2f(up[li * DI]);
      sumdv += dv;
      float du = dv * u;
#pragma unroll
      for (int j = 0; j < 4; ++j) {
        f32x4 bv = bs[li][j];
        f32x4 pv = (f32x4){__expf(dv * A[4 * j]), __expf(dv * A[4 * j + 1]),
                           __expf(dv * A[4 * j + 2]), __expf(dv * A[4 * j + 3])};
        h[j] = pv * h[j] + splat4(du) * bv;
      }
    }
  }
  long hoff = (((long)b * NC + c) * DI + d) * DSTATE;
#pragma unroll
  for (int j = 0; j < 4; ++j) *(f32x4*)(Hbuf + hoff + 4 * j) = h[j];
  sdbuf[((long)b * NC + c) * DI + d] = sumdv;
}

// Phase 2: sequential combine over NC chunk summaries per (b,d,s).
__global__ __launch_bounds__(256) void scan_p2(
    const float* __restrict__ A_log, const float* __restrict__ sdbuf,
    float* __restrict__ Hbuf) {
  const int tid = threadIdx.x;
  const int s = tid & 15;
  const int d = blockIdx.x * 16 + (tid >> 4);
  const int b = blockIdx.y;
  const float A = -__expf(A_log[(long)d * DSTATE + s]);
  float hrun = 0.f;
#pragma unroll
  for (int c = 0; c < NC; ++c) {
    long off = (((long)b * NC + c) * DI + d) * DSTATE + s;
    float Hloc = Hbuf[off];
    float sd = sdbuf[((long)b * NC + c) * DI + d];
    Hbuf[off] = hrun;
    hrun = __expf(A * sd) * hrun + Hloc;
  }
}

// Phase 3: re-run chunk with incoming state; emit gated y (bf16).
__global__ __launch_bounds__(256) void scan_p3(
    const unsigned short* __restrict__ delta, const unsigned short* __restrict__ xcb,
    const unsigned short* __restrict__ zb, const float* __restrict__ proj,
    const float* __restrict__ A_log, const float* __restrict__ D_skip,
    const float* __restrict__ Hbuf, unsigned short* __restrict__ yb) {
  __shared__ __align__(16) f32x4 bs[SCH][8]; // B: [0..3], C: [4..7]
  const int tid = threadIdx.x;
  const int b = blockIdx.z;
  const int c = blockIdx.y;
  const int d = blockIdx.x * 256 + tid;
  const long rowbase = (long)b * LSEQ + (long)c * SCH;

#pragma unroll
  for (int k = 0; k < 2; ++k) {
    int i = tid + k * 256;
    int r = i >> 3, q = i & 7;
    bs[r][q] = *(const f32x4*)(proj + (rowbase + r) * 64 + 32 + q * 4);
  }
  __syncthreads();

  const float* Ap = A_log + (long)d * DSTATE;
  bool fast = true;
#pragma unroll
  for (int j = 0; j < DSTATE; ++j)
    fast = fast && (fabsf(__expf(Ap[j]) - (float)(j + 1)) < 1e-3f);

  long hoff = (((long)b * NC + c) * DI + d) * DSTATE;
  f32x4 h[4];
#pragma unroll
  for (int j = 0; j < 4; ++j) h[j] = *(const f32x4*)(Hbuf + hoff + 4 * j);
  const float Dsk = D_skip[d];

  const unsigned short* dp = delta + rowbase * DI + d;
  const unsigned short* up = xcb + rowbase * DI + d;
  const unsigned short* zp = zb + rowbase * DI + d;
  unsigned short* yp = yb + rowbase * DI + d;

  if (fast) {
    float dvb[PF], ub[PF], zvb[PF];
#pragma unroll
    for (int j = 0; j < PF; ++j) {
      dvb[j] = bfu2f(dp[j * DI]);
      ub[j] = bfu2f(up[j * DI]);
      zvb[j] = bfu2f(zp[j * DI]);
    }
    for (int g = 0; g < SCH; g += PF) {
      // NOTE: prefetch reads up to PF rows past the chunk (inside d_ws; unused)
      float dvn[PF], un[PF], zvn[PF];
#pragma unroll
      for (int j = 0; j < PF; ++j) {
        dvn[j] = bfu2f(dp[(g + PF + j) * DI]);
        un[j] = bfu2f(up[(g + PF + j) * DI]);
        zvn[j] = bfu2f(zp[(g + PF + j) * DI]);
      }
#pragma unroll
      for (int j = 0; j < PF; ++j) {
        float dv = dvb[j], u = ub[j], zv = zvb[j];
        float du = dv * u;
        float q = __expf(-dv);
        float q2 = q * q, q3 = q2 * q, q4 = q2 * q2;
        float q8 = q4 * q4, q12 = q8 * q4;
        f32x4 qv = (f32x4){q, q2, q3, q4};
        f32x4 du4 = splat4(du);
        h[0] = qv * h[0] + du4 * bs[g + j][0];
        h[1] = splat4(q4) * qv * h[1] + du4 * bs[g + j][1];
        h[2] = splat4(q8) * qv * h[2] + du4 * bs[g + j][2];
        h[3] = splat4(q12) * qv * h[3] + du4 * bs[g + j][3];
        f32x4 yv = h[0] * bs[g + j][4] + h[1] * bs[g + j][5];
        yv = yv + h[2] * bs[g + j][6] + h[3] * bs[g + j][7];
        float y = (yv[0] + yv[1]) + (yv[2] + yv[3]);
        float yg = (y + u * Dsk) * (zv / (1.f + __expf(-zv)));
        yp[(g + j) * DI] = f2bfu(yg);
      }
#pragma unroll
      for (int j = 0; j < PF; ++j) { dvb[j] = dvn[j]; ub[j] = un[j]; zvb[j] = zvn[j]; }
    }
  } else {
    float A[16];
#pragma unroll
    for (int j = 0; j < DSTATE; ++j) A[j] = -__expf(Ap[j]);
    for (int li = 0; li < SCH; ++li) {
      float dv = bfu2f(dp[li * DI]);
      float u = bfu2f(up[li * DI]);
      float zv = bfu2f(zp[li * DI]);
      float du = dv * u;
      f32x4 yv = (f32x4){0.f, 0.f, 0.f, 0.f};
#pragma unroll
      for (int j = 0; j < 4; ++j) {
        f32x4 pv = (f32x4){__expf(dv * A[4 * j]), __expf(dv * A[4 * j + 1]),
                           __expf(dv * A[4 * j + 2]), __expf(dv * A[4 * j + 3])};
        h[j] = pv * h[j] + splat4(du) * bs[li][j];
        yv = yv + h[j] * bs[li][4 + j];
      }
      float y = (yv[0] + yv[1]) + (yv[2] + yv[3]);
      float yg = (y + u * Dsk) * (zv / (1.f + __expf(-zv)));
      yp[li * DI] = f2bfu(yg);
    }
  }
}

// -------- fused LayerNorm (stats + apply + transpose), bf16 preLN input --------
__global__ __launch_bounds__(256) void ln_fused_k(
    const unsigned short* __restrict__ pre, const float* __restrict__ gamma,
    const float* __restrict__ beta, float* __restrict__ out) {
  __shared__ float t[32][257];  // 32.9 KB, conflict-free transposed read
  const int tid = threadIdx.x;
  const int b = blockIdx.y;
  const int l0 = blockIdx.x * 32;
  const int r = tid >> 3;        // row in tile
  const int c0 = (tid & 7) * 64; // col base
  const long row = (long)b * LSEQ + l0 + r;

  unsigned short vals[64];
#pragma unroll
  for (int k = 0; k < 8; ++k)
    *(uint4*)(vals + k * 8) = *(const uint4*)(pre + row * DM + c0 + k * 8);

  float f[64];
  float s = 0.f, ss = 0.f;
#pragma unroll
  for (int i = 0; i < 64; ++i) {
    float v = bfu2f(vals[i]);
    f[i] = v;
    s += v;
    ss += v * v;
  }
#pragma unroll
  for (int off = 1; off < 8; off <<= 1) {
    s += __shfl_xor(s, off);
    ss += __shfl_xor(ss, off);
  }
  const float m = s * (1.f / DM);
  const float rstd = rsqrtf(ss * (1.f / DM) - m * m + 1e-5f);

#pragma unroll
  for (int i = 0; i < 64; ++i)
    f[i] = (f[i] - m) * rstd * gamma[c0 + i] + beta[c0 + i];

#pragma unroll
  for (int half = 0; half < 2; ++half) {
    __syncthreads();
    if ((c0 >> 8) == half) {
      int cb = c0 - half * 256;
#pragma unroll
      for (int i = 0; i < 64; ++i) t[r][cb + i] = f[i];
    }
    __syncthreads();
    const int tx = tid & 31;       // l index
    for (int i = tid >> 5; i < 256; i += 8) {
      long dm = half * 256 + i;
      out[((long)b * DM + dm) * LSEQ + l0 + tx] = t[tx][i];
    }
  }
}

extern "C" void kernel_launch(void* const* d_in, const int* in_sizes, int n_in,
                              void* d_out, int out_size, void* d_ws, size_t ws_size,
                              hipStream_t stream) {
  const float* x = (const float*)d_in[0];
  const float* W_in = (const float*)d_in[1];
  const float* conv_w = (const float*)d_in[2];
  const float* conv_b = (const float*)d_in[3];
  const float* W_x = (const float*)d_in[4];
  const float* W_dt = (const float*)d_in[5];
  const float* dt_bias = (const float*)d_in[6];
  const float* A_log = (const float*)d_in[7];
  const float* D_skip = (const float*)d_in[8];
  const float* W_out = (const float*)d_in[9];
  const float* gamma = (const float*)d_in[10];
  const float* beta = (const float*)d_in[11];
  float* out = (float*)d_out;

  char* p = (char*)d_ws;
  auto alloc = [&](size_t bytes) {
    char* r = p;
    p += (bytes + 255) & ~(size_t)255;
    return r;
  };
  unsigned short* xtb = (unsigned short*)alloc((size_t)MROWS * DM * 2);      // 16 MB
  unsigned short* xib = (unsigned short*)alloc((size_t)MROWS * DI * 2);      // 32 MB (reused as yb)
  unsigned short* zb  = (unsigned short*)alloc((size_t)MROWS * DI * 2);      // 32 MB
  unsigned short* xcb = (unsigned short*)alloc((size_t)MROWS * DI * 2);      // 32 MB
  float* proj = (float*)alloc((size_t)MROWS * 64 * 4);                       // 4 MB
  unsigned short* dbuf = (unsigned short*)alloc((size_t)MROWS * DI * 2);     // 32 MB (reused as preLN bf16)
  float* sdbuf = (float*)alloc((size_t)B_SZ * NC * DI * 4);                  // 1 MB
  unsigned short* WinT = (unsigned short*)alloc((size_t)2 * DI * DM * 2);    // 2 MB
  unsigned short* WxT = (unsigned short*)alloc((size_t)64 * DI * 2);
  unsigned short* WoutT = (unsigned short*)alloc((size_t)DM * DI * 2);       // 1 MB
  unsigned short* yb = xib;                 // xi dead after conv
  unsigned short* preLNb = dbuf;            // delta dead after scan (bf16 preLN)
  // Hbuf (16.8 MB) lives in d_out: dead scratch until ln_fused fully overwrites it.
  float* Hbuf = out;

  transpose_x_k<<<dim3(LSEQ / 32, DM / 32, B_SZ), dim3(32, 8), 0, stream>>>(x, xtb);
  wtrans_k<<<dim3(2 * DI / 32, DM / 32), dim3(32, 8), 0, stream>>>(W_in, WinT, 2 * DI, DM);
  wtrans_k<<<dim3(64 / 32, DI / 32), dim3(32, 8), 0, stream>>>(W_x, WxT, 64, DI);
  wtrans_k<<<dim3(DM / 32, DI / 32), dim3(32, 8), 0, stream>>>(W_out, WoutT, DM, DI);

  // xz = xt @ W_in  (M=16384, N=2048, K=512) -> split bf16 stores xi / z
  gemm_bt8<256, 128, 4, 2, 3><<<dim3(2 * DI / 128, MROWS / 256), 512, 0, stream>>>(
      xtb, WinT, xib, zb, nullptr, 2 * DI, DM);
  // conv + silu -> xcb
  conv_silu_k<<<(MROWS * 128) / 256, 256, 0, stream>>>(xib, conv_w, conv_b, xcb);
  // proj = xc @ W_x (M=16384, N=64, K=1024), fp32 out
  gemm_bt<64, 64, 4, 1, 0><<<dim3(1, MROWS / 64), 256, 0, stream>>>(
      xcb, WxT, proj, nullptr, nullptr, 64, DI);
  // delta = softplus(dt_in @ W_dt + bias), bf16 (W via LDS, 16-row batch)
  delta_k<<<dim3(DI / 256, MROWS / 16), 256, 0, stream>>>(proj, W_dt, dt_bias, dbuf);
  // chunked selective scan (1 thread per d, 16 states, PF=4 pipeline)
  scan_p1<<<dim3(DI / 256, NC, B_SZ), 256, 0, stream>>>(dbuf, xcb, proj, A_log, Hbuf, sdbuf);
  scan_p2<<<dim3(DI / 16, B_SZ), 256, 0, stream>>>(A_log, sdbuf, Hbuf);
  scan_p3<<<dim3(DI / 256, NC, B_SZ), 256, 0, stream>>>(dbuf, xcb, zb, proj, A_log, D_skip,
                                                        Hbuf, yb);
  // preLN = y @ W_out + xt (bf16 store; M=16384, N=512, K=1024)
  gemm_bt<128, 128, 2, 2, 2><<<dim3(DM / 128, MROWS / 128), 256, 0, stream>>>(
      yb, WoutT, preLNb, nullptr, xtb, DM, DI);
  // fused LayerNorm + final transpose
  ln_fused_k<<<dim3(LSEQ / 32, B_SZ), 256, 0, stream>>>(preLNb, gamma, beta, out);
}